// Round 1
// baseline (1471.400 us; speedup 1.0000x reference)
//
#include <hip/hip_runtime.h>
#include <math.h>

#define N_Q   4096
#define N_DB  65536
#define DIM   32
#define KNN   5
#define NC    16                 // db chunks
#define QT    8                  // queries per wave
#define CHUNK (N_DB / NC)        // 4096 points per chunk
#define NQG   (N_Q / QT)         // 512 query groups
#define NEG_INF (-1e30f)

// ---------------- kernel 0: db squared norms ----------------
__global__ __launch_bounds__(256) void k_dbsq(const float* __restrict__ db,
                                              float* __restrict__ dbsq) {
    int p = blockIdx.x * 256 + threadIdx.x;
    const float4* v = (const float4*)(db + (size_t)p * DIM);
    float s = 0.f;
#pragma unroll
    for (int j = 0; j < DIM / 4; ++j) {
        float4 t = v[j];
        s += t.x * t.x + t.y * t.y + t.z * t.z + t.w * t.w;
    }
    dbsq[p] = s;
}

// ---------------- kernel 1: fused distance + per-chunk top-5 ----------------
// wave = (query group of 8) x (db chunk of 4096). lane holds one db point per
// 64-pt block; queries come in via wave-uniform s_loads (scalar pipe).
__global__ __launch_bounds__(256) void k_scan(const float* __restrict__ Q,
                                              const float* __restrict__ DB,
                                              const float* __restrict__ DBSQ,
                                              float2* __restrict__ cand) {
    const int tid  = threadIdx.x;
    const int lane = tid & 63;
    // force wave-uniformity so q addressing becomes scalar (s_load)
    const int wIn  = __builtin_amdgcn_readfirstlane(tid >> 6);
    const int chunk = blockIdx.x & (NC - 1);           // XCD-local: 2 chunks/XCD in L2
    const int qg    = (blockIdx.x >> 4) * 4 + wIn;     // [0, 512)
    const int q0    = qg * QT;
    const int pbase = chunk * CHUNK;

    float tm[QT][KNN];   // per-lane top-5 metric (descending; bigger m = nearer)
    int   ti[QT][KNN];
#pragma unroll
    for (int i = 0; i < QT; ++i)
#pragma unroll
        for (int r = 0; r < KNN; ++r) { tm[i][r] = NEG_INF; ti[i][r] = -1; }

    const float* qbase = Q + (size_t)q0 * DIM;

    auto ins = [&](float v, int vi, float (&M)[KNN], int (&I)[KNN]) {
        if (v > M[KNN - 1]) {                 // rare-ish guard, exec-masked body
#pragma unroll
            for (int r = 0; r < KNN; ++r) {   // stable sorted insert (strict >)
                bool gt = (v > M[r]);
                float nm = gt ? v : M[r];  int ni = gt ? vi : I[r];
                float ov = gt ? M[r] : v;  int oi = gt ? I[r] : vi;
                M[r] = nm; I[r] = ni; v = ov; vi = oi;
            }
        }
    };

    for (int blk = 0; blk < CHUNK / 64; ++blk) {
        const int p = pbase + blk * 64 + lane;
        const float4* pv = (const float4*)(DB + (size_t)p * DIM);
        float4 pt[DIM / 4];
#pragma unroll
        for (int j = 0; j < DIM / 4; ++j) pt[j] = pv[j];
        const float nhalf = -0.5f * DBSQ[p];

        const float* qp = qbase;
        asm volatile("" : "+s"(qp));   // defeat LICM: reload q per block, keep SGPR pressure low

#pragma unroll
        for (int qc = 0; qc < QT; qc += 4) {
            float a0 = nhalf, a1 = nhalf, a2 = nhalf, a3 = nhalf;
#pragma unroll
            for (int k4 = 0; k4 < DIM / 4; ++k4) {
                const float4 pk = pt[k4];
                float4 qv0 = *(const float4*)(qp + (qc + 0) * DIM + k4 * 4);
                float4 qv1 = *(const float4*)(qp + (qc + 1) * DIM + k4 * 4);
                float4 qv2 = *(const float4*)(qp + (qc + 2) * DIM + k4 * 4);
                float4 qv3 = *(const float4*)(qp + (qc + 3) * DIM + k4 * 4);
                a0 = fmaf(qv0.x, pk.x, a0); a0 = fmaf(qv0.y, pk.y, a0);
                a0 = fmaf(qv0.z, pk.z, a0); a0 = fmaf(qv0.w, pk.w, a0);
                a1 = fmaf(qv1.x, pk.x, a1); a1 = fmaf(qv1.y, pk.y, a1);
                a1 = fmaf(qv1.z, pk.z, a1); a1 = fmaf(qv1.w, pk.w, a1);
                a2 = fmaf(qv2.x, pk.x, a2); a2 = fmaf(qv2.y, pk.y, a2);
                a2 = fmaf(qv2.z, pk.z, a2); a2 = fmaf(qv2.w, pk.w, a2);
                a3 = fmaf(qv3.x, pk.x, a3); a3 = fmaf(qv3.y, pk.y, a3);
                a3 = fmaf(qv3.z, pk.z, a3); a3 = fmaf(qv3.w, pk.w, a3);
            }
            ins(a0, p, tm[qc + 0], ti[qc + 0]);
            ins(a1, p, tm[qc + 1], ti[qc + 1]);
            ins(a2, p, tm[qc + 2], ti[qc + 2]);
            ins(a3, p, tm[qc + 3], ti[qc + 3]);
        }
    }

    // wave merge: 5 rounds of butterfly argmax (tie-break: smaller index)
#pragma unroll
    for (int qi = 0; qi < QT; ++qi) {
        float wm[KNN]; int wi[KNN];
#pragma unroll
        for (int r = 0; r < KNN; ++r) {
            float hm = tm[qi][0]; int hi = ti[qi][0];
            float bm = hm; int bi = hi;
#pragma unroll
            for (int off = 32; off >= 1; off >>= 1) {
                float om = __shfl_xor(bm, off, 64);
                int   oi = __shfl_xor(bi, off, 64);
                if (om > bm || (om == bm && (unsigned)oi < (unsigned)bi)) { bm = om; bi = oi; }
            }
            if (hi == bi && hm == bm) {       // owner pops (idx is unique)
#pragma unroll
                for (int s = 0; s < KNN - 1; ++s) { tm[qi][s] = tm[qi][s + 1]; ti[qi][s] = ti[qi][s + 1]; }
                tm[qi][KNN - 1] = NEG_INF; ti[qi][KNN - 1] = -1;
            }
            wm[r] = bm; wi[r] = bi;
        }
        if (lane == 0) {
            float2* dst = cand + ((size_t)(q0 + qi) * NC + chunk) * KNN;
#pragma unroll
            for (int r = 0; r < KNN; ++r)
                dst[r] = make_float2(wm[r], __int_as_float(wi[r]));
        }
    }
}

// ---------------- kernel 2: merge 80 candidates, weights, aux blend ----------------
__global__ __launch_bounds__(256) void k_out(const float* __restrict__ Q,
                                             const float* __restrict__ AUX,
                                             const float2* __restrict__ cand,
                                             float* __restrict__ out) {
    const int tid  = threadIdx.x;
    const int lane = tid & 63;
    const int qi   = blockIdx.x * 4 + (tid >> 6);
    const float2* cq = cand + (size_t)qi * (NC * KNN);

    float m1, m2 = NEG_INF; int i1, i2 = -1;
    float2 c1 = cq[lane];
    m1 = c1.x; i1 = __float_as_int(c1.y);
    if (lane < NC * KNN - 64) {               // lanes 0..15 carry candidates 64..79
        float2 c2 = cq[64 + lane];
        m2 = c2.x; i2 = __float_as_int(c2.y);
    }
    if (m2 > m1 || (m2 == m1 && (unsigned)i2 < (unsigned)i1)) {
        float t = m1; m1 = m2; m2 = t; int u = i1; i1 = i2; i2 = u;
    }

    float wm[KNN]; int wi[KNN];
#pragma unroll
    for (int r = 0; r < KNN; ++r) {
        float bm = m1; int bi = i1;
#pragma unroll
        for (int off = 32; off >= 1; off >>= 1) {
            float om = __shfl_xor(bm, off, 64);
            int   oi = __shfl_xor(bi, off, 64);
            if (om > bm || (om == bm && (unsigned)oi < (unsigned)bi)) { bm = om; bi = oi; }
        }
        if (i1 == bi) { m1 = m2; i1 = i2; m2 = NEG_INF; i2 = -1; }  // owner pops
        wm[r] = bm; wi[r] = bi;
    }

    float q2 = 0.f;
    const float4* qv = (const float4*)(Q + (size_t)qi * DIM);
#pragma unroll
    for (int j = 0; j < DIM / 4; ++j) {
        float4 t = qv[j];
        q2 += t.x * t.x + t.y * t.y + t.z * t.z + t.w * t.w;
    }

    float w[KNN], W = 0.f;
#pragma unroll
    for (int r = 0; r < KNN; ++r) {
        float d = sqrtf(fmaxf(q2 - 2.f * wm[r], 0.f));   // dist^2 = q^2 - 2m
        w[r] = 1.f / (d + 1e-6f);
        W += w[r];
    }

    if (lane < DIM) {
        float o = 0.f;
#pragma unroll
        for (int r = 0; r < KNN; ++r)
            o += w[r] * AUX[(size_t)wi[r] * DIM + lane];
        out[(size_t)qi * DIM + lane] = o / W;
    }
}

// ---------------- launch ----------------
extern "C" void kernel_launch(void* const* d_in, const int* in_sizes, int n_in,
                              void* d_out, int out_size, void* d_ws, size_t ws_size,
                              hipStream_t stream) {
    const float* Q   = (const float*)d_in[0];   // [4096, 32]
    const float* DB  = (const float*)d_in[1];   // [65536, 32]
    const float* AUX = (const float*)d_in[2];   // [65536, 32]
    float* out = (float*)d_out;                 // [4096, 32]

    float*  dbsq = (float*)d_ws;                                      // 256 KB
    float2* cand = (float2*)((char*)d_ws + (size_t)N_DB * sizeof(float)); // 2.56 MB

    k_dbsq<<<N_DB / 256, 256, 0, stream>>>(DB, dbsq);
    k_scan<<<(NQG * NC) / 4, 256, 0, stream>>>(Q, DB, dbsq, cand);
    k_out<<<N_Q / 4, 256, 0, stream>>>(Q, AUX, cand, out);
}

// Round 2
// 491.659 us; speedup vs baseline: 2.9927x; 2.9927x over previous
//
#include <hip/hip_runtime.h>
#include <math.h>

#define N_Q   4096
#define N_DB  65536
#define DIM   32
#define KNN   5
#define NEG_INF (-1e30f)

typedef float vf16 __attribute__((ext_vector_type(16)));

// ---------------- kernel 0: db squared norms, pre-scaled by -0.5 ----------------
__global__ __launch_bounds__(256) void k_dbsq(const float* __restrict__ db,
                                              float* __restrict__ dbsq) {
    int p = blockIdx.x * 256 + threadIdx.x;
    const float4* v = (const float4*)(db + (size_t)p * DIM);
    float s = 0.f;
#pragma unroll
    for (int j = 0; j < DIM / 4; ++j) {
        float4 t = v[j];
        s += t.x * t.x + t.y * t.y + t.z * t.z + t.w * t.w;
    }
    dbsq[p] = -0.5f * s;   // metric m = q.d - 0.5*|d|^2 ; acc inits from this
}

// ---------------- kernel 1: lane=query scan, db broadcast via s_load ----------------
// Wave: 64 queries (one per lane, q pinned in 32 VGPRs) x one db chunk.
// db point: 32 floats + nhalf loaded on the SCALAR pipe (inline asm
// s_load_dwordx16), double-buffered, consumed as the SGPR operand of v_fma.
template <int NC>
__global__ __launch_bounds__(256) void k_scan(const float* __restrict__ Q,
                                              const float* __restrict__ DB,
                                              const float* __restrict__ DBSQ,
                                              float* __restrict__ candm,
                                              int* __restrict__ candi) {
    constexpr int CH = N_DB / NC;
    const int tid   = threadIdx.x;
    const int chunk = blockIdx.x % NC;          // low bits -> spread chunks over XCDs
    const int qtile = blockIdx.x / NC;
    const int q     = qtile * 256 + tid;        // this lane's query

    // pin query in VGPRs
    float qv[DIM];
    const float4* qp = (const float4*)(Q + (size_t)q * DIM);
#pragma unroll
    for (int j = 0; j < DIM / 4; ++j) {
        float4 t = qp[j];
        qv[4 * j + 0] = t.x; qv[4 * j + 1] = t.y;
        qv[4 * j + 2] = t.z; qv[4 * j + 3] = t.w;
    }

    float tm[KNN]; int ti[KNN];
#pragma unroll
    for (int r = 0; r < KNN; ++r) { tm[r] = NEG_INF; ti[r] = -1; }

    const int pbase = chunk * CH;

    vf16 A0, B0, A1, B1; float h0, h1;

    auto prefetch = [&](vf16& A, vf16& B, float& h, int p) {
        const float* ptr = DB + (size_t)p * DIM;
        const float* hp  = DBSQ + p;
        asm volatile("s_load_dwordx16 %0, %3, 0x0\n\t"
                     "s_load_dwordx16 %1, %3, 0x40\n\t"
                     "s_load_dword    %2, %4, 0x0"
                     : "=&s"(A), "=&s"(B), "=&s"(h)
                     : "s"(ptr), "s"(hp));
    };

    auto compute = [&](const vf16& A, const vf16& B, float h, int p) {
        float a0 = h, a1 = 0.f;                 // two chains: halve dep latency
#pragma unroll
        for (int k = 0; k < 16; ++k) a0 = fmaf(qv[k],      A[k], a0);
#pragma unroll
        for (int k = 0; k < 16; ++k) a1 = fmaf(qv[16 + k], B[k], a1);
        float m = a0 + a1;
        if (m > tm[KNN - 1]) {                  // exec-masked sorted insert
#pragma unroll
            for (int r = 0; r < KNN; ++r) {
                bool gt = (m > tm[r]);          // strict >: earlier index wins ties
                float nm = gt ? m : tm[r];  int ni = gt ? p : ti[r];
                float ov = gt ? tm[r] : m;  int oi = gt ? ti[r] : p;
                tm[r] = nm; ti[r] = ni; m = ov; p = oi;
            }
        }
    };

    prefetch(A0, B0, h0, pbase);
    for (int j = 0; j < CH; j += 2) {
        asm volatile("s_waitcnt lgkmcnt(0)" : "+s"(A0), "+s"(B0), "+s"(h0));
        prefetch(A1, B1, h1, pbase + j + 1);
        compute(A0, B0, h0, pbase + j);
        asm volatile("s_waitcnt lgkmcnt(0)" : "+s"(A1), "+s"(B1), "+s"(h1));
        if (j + 2 < CH) prefetch(A0, B0, h0, pbase + j + 2);
        compute(A1, B1, h1, pbase + j + 1);
    }

    float* md = candm + ((size_t)q * NC + chunk) * KNN;
    int*   id = candi + ((size_t)q * NC + chunk) * KNN;
#pragma unroll
    for (int r = 0; r < KNN; ++r) { md[r] = tm[r]; id[r] = ti[r]; }
}

// ---------------- kernel 2: merge NC*5 candidates, weights, aux blend ----------------
// One wave per query; lane = chunk (lane >= NC holds empty list).
template <int NC>
__global__ __launch_bounds__(256) void k_out(const float* __restrict__ Q,
                                             const float* __restrict__ AUX,
                                             const float* __restrict__ candm,
                                             const int* __restrict__ candi,
                                             float* __restrict__ out) {
    const int tid  = threadIdx.x;
    const int lane = tid & 63;
    const int qi   = blockIdx.x * 4 + (tid >> 6);

    float hm[KNN]; int hi[KNN];
    if (lane < NC) {
        const float* mp = candm + ((size_t)qi * NC + lane) * KNN;
        const int*   ip = candi + ((size_t)qi * NC + lane) * KNN;
#pragma unroll
        for (int r = 0; r < KNN; ++r) { hm[r] = mp[r]; hi[r] = ip[r]; }
    } else {
#pragma unroll
        for (int r = 0; r < KNN; ++r) { hm[r] = NEG_INF; hi[r] = -1; }
    }

    float wm[KNN]; int wi[KNN];
#pragma unroll
    for (int r = 0; r < KNN; ++r) {
        float bm = hm[0]; int bi = hi[0];
#pragma unroll
        for (int off = 32; off >= 1; off >>= 1) {
            float om = __shfl_xor(bm, off, 64);
            int   oi = __shfl_xor(bi, off, 64);
            if (om > bm || (om == bm && (unsigned)oi < (unsigned)bi)) { bm = om; bi = oi; }
        }
        if (hi[0] == bi) {                      // winner pops (indices unique per chunk)
#pragma unroll
            for (int s = 0; s < KNN - 1; ++s) { hm[s] = hm[s + 1]; hi[s] = hi[s + 1]; }
            hm[KNN - 1] = NEG_INF; hi[KNN - 1] = -1;
        }
        wm[r] = bm; wi[r] = bi;
    }

    float q2 = 0.f;
    const float4* qv = (const float4*)(Q + (size_t)qi * DIM);
#pragma unroll
    for (int j = 0; j < DIM / 4; ++j) {
        float4 t = qv[j];
        q2 += t.x * t.x + t.y * t.y + t.z * t.z + t.w * t.w;
    }

    float w[KNN], W = 0.f;
#pragma unroll
    for (int r = 0; r < KNN; ++r) {
        float d = sqrtf(fmaxf(q2 - 2.f * wm[r], 0.f));   // dist^2 = q^2 - 2m
        w[r] = 1.f / (d + 1e-6f);
        W += w[r];
    }

    if (lane < DIM) {
        float o = 0.f;
#pragma unroll
        for (int r = 0; r < KNN; ++r)
            o += w[r] * AUX[(size_t)wi[r] * DIM + lane];
        out[(size_t)qi * DIM + lane] = o / W;
    }
}

// ---------------- launch ----------------
extern "C" void kernel_launch(void* const* d_in, const int* in_sizes, int n_in,
                              void* d_out, int out_size, void* d_ws, size_t ws_size,
                              hipStream_t stream) {
    const float* Q   = (const float*)d_in[0];
    const float* DB  = (const float*)d_in[1];
    const float* AUX = (const float*)d_in[2];
    float* out = (float*)d_out;

    float* dbsq = (float*)d_ws;

    k_dbsq<<<N_DB / 256, 256, 0, stream>>>(DB, dbsq);

    auto run = [&](auto nc_tag) {
        constexpr int NC = decltype(nc_tag)::value;
        float* candm = (float*)((char*)d_ws + (size_t)N_DB * 4);
        int*   candi = (int*)((char*)candm + (size_t)N_Q * NC * KNN * 4);
        k_scan<NC><<<(N_Q / 256) * NC, 256, 0, stream>>>(Q, DB, dbsq, candm, candi);
        k_out<NC><<<N_Q / 4, 256, 0, stream>>>(Q, AUX, candm, candi, out);
    };

    size_t need64 = (size_t)N_DB * 4 + (size_t)N_Q * 64 * KNN * 8;
    size_t need32 = (size_t)N_DB * 4 + (size_t)N_Q * 32 * KNN * 8;
    if (ws_size >= need64)      run(std::integral_constant<int, 64>{});
    else if (ws_size >= need32) run(std::integral_constant<int, 32>{});
    else                        run(std::integral_constant<int, 16>{});
}

// Round 4
// 145.579 us; speedup vs baseline: 10.1072x; 3.3773x over previous
//
#include <hip/hip_runtime.h>
#include <math.h>

#define N_Q   4096
#define N_DB  65536
#define DIM   32
#define KNN   5
#define NC    32                 // chunks
#define CH    2048               // points per chunk
#define TS    256                // staged tile (points)
#define NSTG  (CH / TS)          // 8 stages per chunk
#define NSUB  (TS / 32)          // 8 subtiles per stage
#define NCAND (NC * 6)           // 192 candidates per query
#define BIAS  256.0f

typedef _Float16 half8 __attribute__((ext_vector_type(8)));
typedef float floatx16 __attribute__((ext_vector_type(16)));

union H8  { half8 h; uint4 u; _Float16 e[8]; };
union F16 { floatx16 v; float4 q4[4]; float f[16]; unsigned u[16]; };

// ---------------- kernel 0: convert to fp16 + norms ----------------
// DBh layout: tile-major [tile=p>>5][group g=dim/8][row=p&31][8 halves]
//   -> A-frag ds_read_b128 is bank-sequential (no LDS conflicts)
// Qh layout: row-major [q][4 groups of 8 halves]
__global__ __launch_bounds__(256) void k_prep(const float* __restrict__ Q,
                                              const float* __restrict__ DB,
                                              uint4* __restrict__ Qh,
                                              uint4* __restrict__ DBh,
                                              float* __restrict__ hdb,
                                              float* __restrict__ dsq) {
    int p = blockIdx.x * 256 + threadIdx.x;          // 0..69631
    bool isdb = p < N_DB;
    const float* src = isdb ? (DB + (size_t)p * DIM) : (Q + (size_t)(p - N_DB) * DIM);
    float v[DIM]; float s = 0.f;
#pragma unroll
    for (int j = 0; j < DIM / 4; ++j) {
        float4 t = ((const float4*)src)[j];
        v[4 * j + 0] = t.x; v[4 * j + 1] = t.y; v[4 * j + 2] = t.z; v[4 * j + 3] = t.w;
        s += t.x * t.x + t.y * t.y + t.z * t.z + t.w * t.w;
    }
    uint4 g[4];
#pragma unroll
    for (int gi = 0; gi < 4; ++gi) {
        H8 hh;
#pragma unroll
        for (int j = 0; j < 8; ++j) hh.e[j] = (_Float16)v[gi * 8 + j];
        g[gi] = hh.u;
    }
    if (isdb) {
        dsq[p] = s;
        hdb[p] = BIAS - 0.5f * s;                    // MFMA C-init: bias + (-0.5*|d|^2)
        int t = p >> 5, r = p & 31;
#pragma unroll
        for (int gi = 0; gi < 4; ++gi) DBh[(size_t)t * 128 + gi * 32 + r] = g[gi];
    } else {
        int q = p - N_DB;
#pragma unroll
        for (int gi = 0; gi < 4; ++gi) Qh[(size_t)q * 4 + gi] = g[gi];
    }
}

// ---------------- kernel 1: MFMA scan + per-chunk approx top-6 ----------------
__device__ __forceinline__ void ld_lds16(const void* g, void* l) {
    __builtin_amdgcn_global_load_lds((const __attribute__((address_space(1))) unsigned*)g,
                                     (__attribute__((address_space(3))) unsigned*)l, 16, 0, 0);
}
__device__ __forceinline__ void ld_lds4(const void* g, void* l) {
    __builtin_amdgcn_global_load_lds((const __attribute__((address_space(1))) unsigned*)g,
                                     (__attribute__((address_space(3))) unsigned*)l, 4, 0, 0);
}

__global__ __launch_bounds__(256) void k_scan(const uint4* __restrict__ Qh,
                                              const uint4* __restrict__ DBh,
                                              const float* __restrict__ hdb,
                                              unsigned* __restrict__ cand) {
    __shared__ uint4 dbs[2][1024];     // 2 x 16 KB db tile (tile-major image)
    __shared__ float hbs[2][TS];       // 2 x 1 KB  C-init values
    const int tid = threadIdx.x, lane = tid & 63, w = tid >> 6;
    const int h = lane >> 5, qcol = lane & 31;
    const int chunk = blockIdx.x & (NC - 1);         // blocks of same chunk land on same XCD
    const int qb = blockIdx.x >> 5;
    const int q = qb * 128 + w * 32 + qcol;
    const int pbase = chunk * CH;

    // persistent B-frags: B[k][n]: lane holds n=qcol, k = h*8+j  (MFMA1: dims 0..15, MFMA2: 16..31)
    H8 b1, b2;
    b1.u = Qh[(size_t)q * 4 + h];
    b2.u = Qh[(size_t)q * 4 + 2 + h];

    float tk[6];                                     // packed top-6 (descending), reals > 0
#pragma unroll
    for (int r = 0; r < 6; ++r) tk[r] = 0.f;

    auto stage = [&](int buf, int t) {
        const char* s = (const char*)DBh + (size_t)pbase * 64 + (size_t)t * 16384 + w * 4096 + lane * 16;
        char* d = (char*)&dbs[buf][0] + w * 4096;    // wave-uniform base; HW scatters +lane*16
        ld_lds16(s, d);
        ld_lds16(s + 1024, d + 1024);
        ld_lds16(s + 2048, d + 2048);
        ld_lds16(s + 3072, d + 3072);
        ld_lds4(hdb + pbase + t * TS + w * 64 + lane, (char*)&hbs[buf][0] + w * 256);
    };

    constexpr int ROWC[16] = {0,1,2,3, 8,9,10,11, 16,17,18,19, 24,25,26,27}; // no bit 2 (bit 2 = h)

    stage(0, 0);
    for (int t = 0; t < NSTG; ++t) {
        __syncthreads();                             // drains vmcnt for buf(t) loads (issued a full stage ago)
        if (t + 1 < NSTG) stage((t + 1) & 1, t + 1);
        const int buf = t & 1;
        const char* base = (const char*)&dbs[buf][0];
#pragma unroll
        for (int sub = 0; sub < NSUB; ++sub) {
            const char* tb = base + sub * 2048;
            H8 a1, a2;                               // A[row][k]: row=lane&31, k-group = h (and 2+h)
            a1.u = *(const uint4*)(tb + h * 512 + (lane & 31) * 16);
            a2.u = *(const uint4*)(tb + 1024 + h * 512 + (lane & 31) * 16);
            F16 c0;
            const float* hb = &hbs[buf][sub * 32 + 4 * h];
            c0.q4[0] = *(const float4*)(hb + 0);     // rows 4h..4h+3   -> regs 0..3
            c0.q4[1] = *(const float4*)(hb + 8);     // rows 8+4h..     -> regs 4..7
            c0.q4[2] = *(const float4*)(hb + 16);
            c0.q4[3] = *(const float4*)(hb + 24);
            floatx16 acc = __builtin_amdgcn_mfma_f32_32x32x16_f16(a1.h, b1.h, c0.v, 0, 0, 0);
            acc = __builtin_amdgcn_mfma_f32_32x32x16_f16(a2.h, b2.h, acc, 0, 0, 0);
            // pack 11-bit (tile,row) id into low mantissa bits — CLEAR first (R3 bug:
            // OR without clearing left score bits in the id field -> garbage id recovery)
            F16 pk; pk.v = acc;
            const unsigned meta = (unsigned)(((t * NSUB + sub) << 5) | (h << 2));
            float p[16];
#pragma unroll
            for (int r = 0; r < 16; ++r)
                p[r] = __uint_as_float((pk.u[r] & ~2047u) | meta | (unsigned)ROWC[r]);
            // true top-2 of 16 via (max,min) tournament
            float hi[8], lo[8];
#pragma unroll
            for (int i = 0; i < 8; ++i) { hi[i] = fmaxf(p[2*i], p[2*i+1]); lo[i] = fminf(p[2*i], p[2*i+1]); }
            float H4[4], L4[4];
#pragma unroll
            for (int i = 0; i < 4; ++i) {
                H4[i] = fmaxf(hi[2*i], hi[2*i+1]);
                L4[i] = fmaxf(fmaxf(lo[2*i], lo[2*i+1]), fminf(hi[2*i], hi[2*i+1]));
            }
            float H2[2], L2[2];
#pragma unroll
            for (int i = 0; i < 2; ++i) {
                H2[i] = fmaxf(H4[2*i], H4[2*i+1]);
                L2[i] = fmaxf(fmaxf(L4[2*i], L4[2*i+1]), fminf(H4[2*i], H4[2*i+1]));
            }
            float c1 = fmaxf(H2[0], H2[1]);
            float c2 = fmaxf(fmaxf(L2[0], L2[1]), fminf(H2[0], H2[1]));
            // branchless sorted-6 insert
#pragma unroll
            for (int i = 0; i < 6; ++i) { float mx = fmaxf(tk[i], c1); c1 = fminf(tk[i], c1); tk[i] = mx; }
#pragma unroll
            for (int i = 0; i < 6; ++i) { float mx = fmaxf(tk[i], c2); c2 = fminf(tk[i], c2); tk[i] = mx; }
        }
    }
    // merge the two half-lane streams (same query, disjoint rows)
    float other[6];
#pragma unroll
    for (int i = 0; i < 6; ++i) other[i] = __shfl_xor(tk[i], 32, 64);
#pragma unroll
    for (int i = 0; i < 6; ++i) {
        float val = other[i];
#pragma unroll
        for (int j = 0; j < 6; ++j) { float mx = fmaxf(tk[j], val); val = fminf(tk[j], val); tk[j] = mx; }
    }
    if (h == 0) {
        unsigned* dst = cand + ((size_t)q * NC + chunk) * 6;
#pragma unroll
        for (int r = 0; r < 6; ++r) dst[r] = __float_as_uint(tk[r]);
    }
}

// ---------------- kernel 2: global approx top-12, exact rescore, top-5, blend ----------------
__global__ __launch_bounds__(256) void k_merge(const float* __restrict__ Q,
                                               const float* __restrict__ DB,
                                               const float* __restrict__ AUX,
                                               const float* __restrict__ dsq,
                                               const unsigned* __restrict__ cand,
                                               float* __restrict__ out) {
    const int tid = threadIdx.x, lane = tid & 63, w = tid >> 6;
    const int q = blockIdx.x * 4 + w;
    const unsigned* cq = cand + (size_t)q * NCAND;

    float s0, s1, s2; int c0, c1, c2;
    {
        int p0 = lane * 3, p1 = p0 + 1, p2 = p0 + 2;
        s0 = __uint_as_float(cq[p0]); c0 = p0 / 6;
        s1 = __uint_as_float(cq[p1]); c1 = p1 / 6;
        s2 = __uint_as_float(cq[p2]); c2 = p2 / 6;
    }
    // sort3 descending by (score, then smaller chunk)
    if (s1 > s0 || (s1 == s0 && c1 < c0)) { float t = s0; s0 = s1; s1 = t; int u = c0; c0 = c1; c1 = u; }
    if (s2 > s1 || (s2 == s1 && c2 < c1)) { float t = s1; s1 = s2; s2 = t; int u = c1; c1 = c2; c2 = u; }
    if (s1 > s0 || (s1 == s0 && c1 < c0)) { float t = s0; s0 = s1; s1 = t; int u = c0; c0 = c1; c1 = u; }

    float wv[12]; int wc[12];
#pragma unroll
    for (int r = 0; r < 12; ++r) {
        float bv = s0; int bc = c0;
#pragma unroll
        for (int off = 32; off >= 1; off >>= 1) {
            float ov = __shfl_xor(bv, off, 64);
            int   oc = __shfl_xor(bc, off, 64);
            if (ov > bv || (ov == bv && oc < bc)) { bv = ov; bc = oc; }
        }
        wv[r] = bv; wc[r] = bc;
        if (s0 == bv && c0 == bc) { s0 = s1; c0 = c1; s1 = s2; c1 = c2; s2 = -1.f; c2 = 1 << 29; }
    }

    // exact fp32 rescore of the 12 (lanes 0..11)
    float dist = 1e30f; int dbi = 0x7fffffff;
    if (lane < 12) {
        unsigned u = __float_as_uint(wv[lane]);
        int b = (u >> 5) & 63, row = u & 31;
        dbi = wc[lane] * CH + b * 32 + row;
        const float4* dp = (const float4*)(DB + (size_t)dbi * DIM);
        const float4* qp = (const float4*)(Q + (size_t)q * DIM);
        float dot = 0.f, qs = 0.f;
#pragma unroll
        for (int j = 0; j < DIM / 4; ++j) {
            float4 a = qp[j], d = dp[j];
            dot += a.x * d.x + a.y * d.y + a.z * d.z + a.w * d.w;
            qs  += a.x * a.x + a.y * a.y + a.z * a.z + a.w * a.w;
        }
        float d2 = qs + dsq[dbi] - 2.f * dot;
        dist = sqrtf(fmaxf(d2, 0.f));
    }
    // exact top-5 by (dist, smaller index) — matches reference tie-break
    float wd[KNN]; int wi[KNN];
#pragma unroll
    for (int r = 0; r < KNN; ++r) {
        float bd = dist; int bi = dbi;
#pragma unroll
        for (int off = 32; off >= 1; off >>= 1) {
            float od = __shfl_xor(bd, off, 64);
            int   oi = __shfl_xor(bi, off, 64);
            if (od < bd || (od == bd && oi < bi)) { bd = od; bi = oi; }
        }
        wd[r] = bd; wi[r] = bi;
        if (dist == bd && dbi == bi) dist = 1e30f;
    }
    float ww[KNN], W = 0.f;
#pragma unroll
    for (int r = 0; r < KNN; ++r) { ww[r] = 1.f / (wd[r] + 1e-6f); W += ww[r]; }
    if (lane < DIM) {
        float o = 0.f;
#pragma unroll
        for (int r = 0; r < KNN; ++r) o += ww[r] * AUX[(size_t)wi[r] * DIM + lane];
        out[(size_t)q * DIM + lane] = o / W;
    }
}

// ---------------- launch ----------------
extern "C" void kernel_launch(void* const* d_in, const int* in_sizes, int n_in,
                              void* d_out, int out_size, void* d_ws, size_t ws_size,
                              hipStream_t stream) {
    const float* Q   = (const float*)d_in[0];
    const float* DB  = (const float*)d_in[1];
    const float* AUX = (const float*)d_in[2];
    float* out = (float*)d_out;

    char* ws = (char*)d_ws;
    uint4*    Qh   = (uint4*)ws;                                  ws += (size_t)N_Q * 4 * 16;     // 256 KB
    uint4*    DBh  = (uint4*)ws;                                  ws += (size_t)(N_DB / 32) * 128 * 16; // 4 MB
    float*    hdb  = (float*)ws;                                  ws += (size_t)N_DB * 4;         // 256 KB
    float*    dsq  = (float*)ws;                                  ws += (size_t)N_DB * 4;         // 256 KB
    unsigned* cand = (unsigned*)ws;                               // 4096*192*4 = 3 MB

    k_prep<<<(N_DB + N_Q) / 256, 256, 0, stream>>>(Q, DB, Qh, DBh, hdb, dsq);
    k_scan<<<(N_Q / 128) * NC, 256, 0, stream>>>(Qh, DBh, hdb, cand);
    k_merge<<<N_Q / 4, 256, 0, stream>>>(Q, DB, AUX, dsq, cand, out);
}